// Round 9
// baseline (264.653 us; speedup 1.0000x reference)
//
#include <hip/hip_runtime.h>

#define NP 32
#define NROWS 65536

typedef _Float16 f16x8 __attribute__((ext_vector_type(8)));
typedef _Float16 f16x4 __attribute__((ext_vector_type(4)));
typedef _Float16 f16x2 __attribute__((ext_vector_type(2)));
typedef float    f32x4 __attribute__((ext_vector_type(4)));

#if __has_builtin(__builtin_amdgcn_rcpf)
#define FAST_RCP(x) __builtin_amdgcn_rcpf(x)
#else
#define FAST_RCP(x) (1.0f / (x))
#endif

// tanh(x) = 1 - 2/(e^{2x}+1). No clamp needed: e->inf gives 1, e->0 gives -1.
__device__ __forceinline__ float fast_tanh(float v) {
    float e = __expf(2.0f * v);
    return fmaf(-2.0f, FAST_RCP(e + 1.0f), 1.0f);
}

// v_cvt_pkrtz_f16_f32 returns __fp16x2; bit_cast to our _Float16 vectors.
__device__ __forceinline__ f16x4 pack4(float c0, float c1, float c2, float c3) {
    const f16x2 p01 = __builtin_bit_cast(f16x2, __builtin_amdgcn_cvt_pkrtz(c0, c1));
    const f16x2 p23 = __builtin_bit_cast(f16x2, __builtin_amdgcn_cvt_pkrtz(c2, c3));
    return __builtin_shufflevector(p01, p23, 0, 1, 2, 3);
}

// ---------------- prepacked weight storage (device globals) ----------------
// 17 MFMA steps per p: B1:s0-3 (bias folded into k=31 col, input=1)
//   B2:s4-7  B3:s8-9  B4:s10  A2:s11-14  A3:s15  A4:s16   (order: Mt, ks)
// A-frag layout: A[row=lane&15][k=8*(lane>>4)+e]; C: out=16Mt+4*(l>>4)+j, n=l&15.
// 9 bias steps (C-layout): B2:0-1 B3:2-3 B4:4 A2:5-6 A3:7 A4:8
__device__ __align__(16) _Float16 g_frag[NP][17 * 2 * 64 * 8]; // hi/lo pairs
__device__ __align__(16) float    g_bias[NP][9 * 64 * 4];
__device__ __align__(16) float    g_a1w [NP][4 * 64 * 4];
__device__ __align__(16) float    g_a1b [NP][4 * 64 * 4];
// fin: [0..15]=W56 (Wb6·Wb5 folded), [16]=b56, [17..24]=Wa5, [25]=ba5
__device__ __align__(16) float    g_fin [NP][32];

__global__ void prep_frags(
    const float* __restrict__ Wa1, const float* __restrict__ ba1,
    const float* __restrict__ Wa2, const float* __restrict__ ba2,
    const float* __restrict__ Wa3, const float* __restrict__ ba3,
    const float* __restrict__ Wa4, const float* __restrict__ ba4,
    const float* __restrict__ Wa5, const float* __restrict__ ba5,
    const float* __restrict__ Wb1, const float* __restrict__ bb1,
    const float* __restrict__ Wb2, const float* __restrict__ bb2,
    const float* __restrict__ Wb3, const float* __restrict__ bb3,
    const float* __restrict__ Wb4, const float* __restrict__ bb4,
    const float* __restrict__ Wb5, const float* __restrict__ bb5,
    const float* __restrict__ Wb6, const float* __restrict__ bb6) {
    const int p = blockIdx.x;
    const int l = threadIdx.x;          // 0..63
    const int g = l >> 4, q = l & 15;

    const int sw[17]  = {0,0,0,0, 1,1,1,1, 2,2, 3, 4,4,4,4, 5, 6};
    const int sMt[17] = {0,1,2,3, 0,0,1,1, 0,1, 0, 0,0,1,1, 0, 0};
    const int sks[17] = {0,0,0,0, 0,1,0,1, 0,0, 0, 0,1,0,1, 0, 0};
    const int OO[7] = {64,32,32,16,32,16, 8};
    const int II[7] = {31,64,32,32,64,32,16};
    const float* WS[7] = {Wb1 + p*1984, Wb2 + p*2048, Wb3 + p*1024,
                          Wb4 + p*512,  Wa2 + p*2048, Wa3 + p*512,
                          Wa4 + p*128};
    const float* b1s = bb1 + p*64;
    for (int s = 0; s < 17; ++s) {
        const int w = sw[s], O = OO[w], I = II[w];
        const float* W = WS[w];
        for (int e = 0; e < 8; ++e) {
            const int kk = 32*sks[s] + 8*g + e;   // K index
            const int o  = 16*sMt[s] + q;         // out (= A row)
            float wv = 0.0f;
            if (o < O) {
                if (w == 0)  // B1: col 31 carries the bias (input slot = 1.0)
                    wv = (kk < 31) ? W[o*31 + kk] : (kk == 31 ? b1s[o] : 0.0f);
                else
                    wv = (kk < I) ? W[o*I + kk] : 0.0f;
            }
            const _Float16 hi = (_Float16)wv;
            const _Float16 lo = (_Float16)(wv - (float)hi);
            g_frag[p][((s*2 + 0)*64 + l)*8 + e] = hi;
            g_frag[p][((s*2 + 1)*64 + l)*8 + e] = lo;
        }
    }
    const int bw[9]  = {0,0, 1,1, 2, 3,3, 4, 5};
    const int bMt[9] = {0,1, 0,1, 0, 0,1, 0, 0};
    const float* BS[6] = {bb2 + p*32, bb3 + p*32, bb4 + p*16,
                          ba2 + p*32, ba3 + p*16, ba4 + p*8};
    const int BO[6] = {32,32,16,32,16,8};
    for (int bs = 0; bs < 9; ++bs) {
        const int w = bw[bs];
        for (int j = 0; j < 4; ++j) {
            const int o = 16*bMt[bs] + 4*g + j;
            g_bias[p][(bs*64 + l)*4 + j] = (o < BO[w]) ? BS[w][o] : 0.0f;
        }
    }
    for (int Mt = 0; Mt < 4; ++Mt)
        for (int j = 0; j < 4; ++j) {
            const int o = 16*Mt + 4*g + j;
            g_a1w[p][(Mt*64 + l)*4 + j] = Wa1[p*64 + o];
            g_a1b[p][(Mt*64 + l)*4 + j] = ba1[p*64 + o];
        }
    if (l == 0) {
        // fold B5 (16->8) and B6 (8->1): W56 = Wb6·Wb5, b56 = Wb6·bb5 + bb6
        for (int i = 0; i < 16; ++i) {
            float s = 0.0f;
            for (int o = 0; o < 8; ++o)
                s += Wb6[p*8 + o] * Wb5[p*128 + o*16 + i];
            g_fin[p][i] = s;
        }
        float s = bb6[p];
        for (int o = 0; o < 8; ++o) s += Wb6[p*8 + o] * bb5[p*8 + o];
        g_fin[p][16] = s;
        for (int e = 0; e < 8; ++e) g_fin[p][17 + e] = Wa5[p*8 + e];
        g_fin[p][25] = ba5[p];
    }
}

// ---------------- main kernel ----------------------------------------------
// Wave = 32 rows (2 tiles of 16). The A and B encoder chains are INDEPENDENT;
// their steps are interleaved so each wave always has a second instruction
// stream to issue while the other chain waits on MFMA/LDS latency (round 8
// was latency-bound: one serial chain, both pipes <=50%).
// 3 wave-private planes: W0 (64-col, shared by B1-out then A1-out via
// same-wave in-order LDS read-then-write), N0 (B chain), N1 (A chain).
#define SW 68   // wide plane stride (halves)
#define SN 36   // narrow plane stride

template <int KS, int SSTR>
__device__ __forceinline__ void read_bf(const _Float16* src, f16x8 (&bf)[2][2],
                                        int q, int g) {
#pragma unroll
    for (int t = 0; t < 2; ++t)
#pragma unroll
        for (int ks = 0; ks < KS; ++ks) {
            const _Float16* a = src + (16*t + q)*SSTR + 32*ks + 8*g;
            const f16x4 v0 = *(const f16x4*)(a);
            const f16x4 v1 = *(const f16x4*)(a + 4);
            bf[t][ks] = __builtin_shufflevector(v0, v1, 0,1,2,3,4,5,6,7);
        }
}

// C[out=16Mt+4g+j][n=16t+q] = act((Whi+Wlo)·B + bias) -> dst plane (f16).
// Accumulator is INITIALIZED with the bias vector (saves the epilogue add).
template <int MT, int KS, int ACT, bool ZPAD, bool HASBIAS, int DSTR>
__device__ __forceinline__ void mfma_block(const _Float16* __restrict__ frag,
                                           const float* __restrict__ bias,
                                           int s0, int b0,
                                           const f16x8 (&bf)[2][2],
                                           _Float16* dst, int q, int g, int l) {
#pragma unroll
    for (int Mt = 0; Mt < MT; ++Mt) {
        f32x4 binit = {0.f,0.f,0.f,0.f};
        if (HASBIAS) binit = *(const f32x4*)(bias + ((b0 + Mt)*64 + l)*4);
        f32x4 a0 = binit, a1 = binit;
#pragma unroll
        for (int ks = 0; ks < KS; ++ks) {
            const int s = s0 + Mt*KS + ks;
            const f16x8 whi = *(const f16x8*)(frag + ((s*2 + 0)*64 + l)*8);
            const f16x8 wlo = *(const f16x8*)(frag + ((s*2 + 1)*64 + l)*8);
            a0 = __builtin_amdgcn_mfma_f32_16x16x32_f16(wlo, bf[0][ks], a0, 0,0,0);
            a0 = __builtin_amdgcn_mfma_f32_16x16x32_f16(whi, bf[0][ks], a0, 0,0,0);
            a1 = __builtin_amdgcn_mfma_f32_16x16x32_f16(wlo, bf[1][ks], a1, 0,0,0);
            a1 = __builtin_amdgcn_mfma_f32_16x16x32_f16(whi, bf[1][ks], a1, 0,0,0);
        }
#pragma unroll
        for (int t = 0; t < 2; ++t) {
            const f32x4 av = t ? a1 : a0;
            float c[4];
#pragma unroll
            for (int j = 0; j < 4; ++j) {
                float v = av[j];
                if (ACT == 1) v = fmaxf(v, 0.0f);
                if (ACT == 2) v = fast_tanh(v);
                c[j] = v;
            }
            const f16x4 o4 = pack4(c[0], c[1], c[2], c[3]);
            *(f16x4*)(dst + (16*t + q)*DSTR + 16*Mt + 4*g) = o4;
        }
    }
    if (ZPAD) {   // zero k=16..31 so next layer can read a padded K=32
        const f16x4 z = {(_Float16)0, (_Float16)0, (_Float16)0, (_Float16)0};
#pragma unroll
        for (int t = 0; t < 2; ++t)
            *(f16x4*)(dst + (16*t + q)*DSTR + 16 + 4*g) = z;
    }
}

__global__ __launch_bounds__(256, 4) void mlp_mfma(
    const float* __restrict__ x, float* __restrict__ out) {
    __shared__ __align__(16) _Float16 ldsW [4][32 * SW];  // 17408 B
    __shared__ __align__(16) _Float16 ldsN0[4][32 * SN];  //  9216 B
    __shared__ __align__(16) _Float16 ldsN1[4][32 * SN];  //  9216 B -> 35840/block, 4 blocks/CU

    // Block remap: the 32 p-blocks of one row chunk are consecutive on the
    // same XCD so partial 8B output writes merge in that XCD's L2
    // (verified round 7: WRITE_SIZE 162 -> 16.4 MB).
    const int L   = blockIdx.x;          // 0..16383
    const int xcd = L & 7;
    const int m   = L >> 3;
    const int p   = m & 31;              // feature
    const int rc  = xcd + 8 * (m >> 5);  // row chunk 0..511
    const int wv  = threadIdx.x >> 6;
    const int l   = threadIdx.x & 63;
    const int g   = l >> 4, q = l & 15;
    const int row0 = rc * 128 + wv * 32;

    _Float16* W0 = ldsW[wv];
    _Float16* N0 = ldsN0[wv];
    _Float16* N1 = ldsN1[wv];
    const _Float16* frag = g_frag[p];
    const float*    bias = g_bias[p];
    const float*    fin  = g_fin[p];

    f16x8 bfB[2][2], bfA[2][2];
    float xa[2];

    // ---- B1 B-frag from x (leave-one-out, k=31 slot = 1.0 = bias column);
    //      also grab xa for the A chain while the row is hot in L1.
#pragma unroll
    for (int t = 0; t < 2; ++t) {
        const int grow = row0 + 16*t + q;
        const float* xr = x + grow * NP;
#pragma unroll
        for (int e = 0; e < 8; ++e) {
            const int k = 8*g + e;
            const float xv = (k < 31) ? xr[k + (k >= p ? 1 : 0)] : 1.0f;
            bfB[t][0][e] = (_Float16)xv;
        }
        xa[t] = xr[p];
    }

    // ==================== interleaved A/B schedule ==========================
    // B1: 31->64 relu (bias folded in weights)
    mfma_block<4,1,1,false,false,SW>(frag, bias,  0, 0, bfB, W0, q, g, l);
    // B2 frag read (must precede A1's overwrite of W0; same-wave LDS is in-order)
    read_bf<2, SW>(W0, bfB, q, g);

    // A1: 1->64 relu on VALU -> W0 (reuse after read)
#pragma unroll
    for (int t = 0; t < 2; ++t) {
#pragma unroll
        for (int Mt = 0; Mt < 4; ++Mt) {
            const f32x4 w4 = *(const f32x4*)(g_a1w[p] + (Mt*64 + l)*4);
            const f32x4 b4 = *(const f32x4*)(g_a1b[p] + (Mt*64 + l)*4);
            float c[4];
#pragma unroll
            for (int j = 0; j < 4; ++j)
                c[j] = fmaxf(fmaf(w4[j], xa[t], b4[j]), 0.0f);
            const f16x4 o4 = pack4(c[0], c[1], c[2], c[3]);
            *(f16x4*)(W0 + (16*t + q)*SW + 16*Mt + 4*g) = o4;
        }
    }

    // B2: 64->32 tanh -> N0
    mfma_block<2,2,2,false,true,SN>(frag, bias,  4, 0, bfB, N0, q, g, l);
    // A2 frag read from W0
    read_bf<2, SW>(W0, bfA, q, g);
    // A2: 64->32 tanh -> N1
    mfma_block<2,2,2,false,true,SN>(frag, bias, 11, 5, bfA, N1, q, g, l);
    // B3 frag read from N0
    read_bf<1, SN>(N0, bfB, q, g);
    // B3: 32->32 tanh -> N0 (WAR on same wave: safe)
    mfma_block<2,1,2,false,true,SN>(frag, bias,  8, 2, bfB, N0, q, g, l);
    // A3 frag read from N1
    read_bf<1, SN>(N1, bfA, q, g);
    // A3: 32->16 tanh (+zero-pad K to 32) -> N1
    mfma_block<1,1,2,true, true,SN>(frag, bias, 15, 7, bfA, N1, q, g, l);
    // B4 frag read from N0
    read_bf<1, SN>(N0, bfB, q, g);
    // B4: 32->16 tanh -> N0
    mfma_block<1,1,2,false,true,SN>(frag, bias, 10, 4, bfB, N0, q, g, l);
    // A4 frag read from N1
    read_bf<1, SN>(N1, bfA, q, g);
    // A4: 16->8 tanh -> N1
    mfma_block<1,1,2,false,true,SN>(frag, bias, 16, 8, bfA, N1, q, g, l);

    // B5+B6 folded: 16->1 dot on VALU (reads B4 out in N0)
    float bvv[2];
#pragma unroll
    for (int t = 0; t < 2; ++t) {
        const _Float16* a = N0 + (16*t + q)*SN;
        float s = fin[16];
#pragma unroll
        for (int e = 0; e < 16; ++e) s = fmaf(fin[e], (float)a[e], s);
        bvv[t] = s;
    }

    // A5: 8->1 dot (reads A4 out in N1) + interleaved (a,b) store, lane-group 0
#pragma unroll
    for (int t = 0; t < 2; ++t) {
        const _Float16* a = N1 + (16*t + q)*SN;
        float s = fin[25];
#pragma unroll
        for (int e = 0; e < 8; ++e) s = fmaf(fin[17 + e], (float)a[e], s);
        if (g == 0) {
            const int grow = row0 + 16*t + q;
            reinterpret_cast<float2*>(out)[(size_t)grow * NP + p] =
                make_float2(s, bvv[t]);
        }
    }
}

extern "C" void kernel_launch(void* const* d_in, const int* in_sizes, int n_in,
                              void* d_out, int out_size, void* d_ws,
                              size_t ws_size, hipStream_t stream) {
    const float* x   = (const float*)d_in[0];
    const float* Wa1 = (const float*)d_in[1];
    const float* ba1 = (const float*)d_in[2];
    const float* Wa2 = (const float*)d_in[3];
    const float* ba2 = (const float*)d_in[4];
    const float* Wa3 = (const float*)d_in[5];
    const float* ba3 = (const float*)d_in[6];
    const float* Wa4 = (const float*)d_in[7];
    const float* ba4 = (const float*)d_in[8];
    const float* Wa5 = (const float*)d_in[9];
    const float* ba5 = (const float*)d_in[10];
    const float* Wb1 = (const float*)d_in[11];
    const float* bb1 = (const float*)d_in[12];
    const float* Wb2 = (const float*)d_in[13];
    const float* bb2 = (const float*)d_in[14];
    const float* Wb3 = (const float*)d_in[15];
    const float* bb3 = (const float*)d_in[16];
    const float* Wb4 = (const float*)d_in[17];
    const float* bb4 = (const float*)d_in[18];
    const float* Wb5 = (const float*)d_in[19];
    const float* bb5 = (const float*)d_in[20];
    const float* Wb6 = (const float*)d_in[21];
    const float* bb6 = (const float*)d_in[22];

    prep_frags<<<dim3(NP), dim3(64), 0, stream>>>(
        Wa1, ba1, Wa2, ba2, Wa3, ba3, Wa4, ba4, Wa5, ba5,
        Wb1, bb1, Wb2, bb2, Wb3, bb3, Wb4, bb4, Wb5, bb5, Wb6, bb6);

    mlp_mfma<<<dim3(NROWS / 128 * NP), 256, 0, stream>>>(x, (float*)d_out);
}